// Round 1
// baseline (707.486 us; speedup 1.0000x reference)
//
#include <hip/hip_runtime.h>

#define RNN_H 32
#define RNN_T 2048
#define RNN_B 512
#define RNN_C 10

// tanh(x) = 1 - 2/(exp(2x)+1); exp2 overflow -> inf -> rcp -> 0 -> +1; underflow -> 0 -> -1.
__device__ __forceinline__ float fast_tanh(float x) {
    float e = __builtin_amdgcn_exp2f(x * 2.88539008177792681472f); // 2*log2(e)
    return fmaf(-2.0f, __builtin_amdgcn_rcpf(e + 1.0f), 1.0f);
}

__global__ __launch_bounds__(64) void rnn2_kernel(
    const float* __restrict__ x,
    const float* __restrict__ W_ih0, const float* __restrict__ W_hh0,
    const float* __restrict__ b_ih0, const float* __restrict__ b_hh0,
    const float* __restrict__ W_ih1, const float* __restrict__ W_hh1,
    const float* __restrict__ b_ih1, const float* __restrict__ b_hh1,
    const float* __restrict__ fc_w, const float* __restrict__ fc_b,
    float* __restrict__ out)
{
    const int b    = blockIdx.x;
    const int lane = threadIdx.x;        // 0..63, one wave per block/batch
    const int j    = lane & 31;          // output index
    const int k0   = (lane >> 5) * 16;   // this lane's k-half

    __shared__ float h1s[RNN_H];
    __shared__ float h2s[RNN_H];

    // Weights in registers: row j, cols [k0, k0+16) of each matrix.
    float4 wih0[4], whh0[4], wih1[4], whh1[4];
#pragma unroll
    for (int q = 0; q < 4; ++q) {
        wih0[q] = *(const float4*)&W_ih0[j * RNN_H + k0 + q * 4];
        whh0[q] = *(const float4*)&W_hh0[j * RNN_H + k0 + q * 4];
        wih1[q] = *(const float4*)&W_ih1[j * RNN_H + k0 + q * 4];
        whh1[q] = *(const float4*)&W_hh1[j * RNN_H + k0 + q * 4];
    }
    const float bias1 = b_ih0[j] + b_hh0[j];
    const float bias2 = b_ih1[j] + b_hh1[j];

    if (lane < RNN_H) { h1s[lane] = 0.0f; h2s[lane] = 0.0f; }
    __syncthreads();  // single wave: cheap; makes zero-init visible

    const float* xb = x + (size_t)b * RNN_T * RNN_H + k0;

    // x prefetch ring, depth 4 (per lane: its 16 floats of each step)
    float4 xr[4][4];
#pragma unroll
    for (int s = 0; s < 4; ++s)
#pragma unroll
        for (int q = 0; q < 4; ++q)
            xr[s][q] = *(const float4*)&xb[s * RNN_H + q * 4];

#define RNN_STEP(S, TT, RELOAD)                                              \
    {                                                                        \
        /* layer 1: x-dot (ring regs) and h1-dot (LDS broadcast) */          \
        float accx = 0.f, acch = 0.f;                                        \
        _Pragma("unroll")                                                    \
        for (int q = 0; q < 4; ++q) {                                        \
            accx = fmaf(wih0[q].x, xr[S][q].x, accx);                        \
            accx = fmaf(wih0[q].y, xr[S][q].y, accx);                        \
            accx = fmaf(wih0[q].z, xr[S][q].z, accx);                        \
            accx = fmaf(wih0[q].w, xr[S][q].w, accx);                        \
        }                                                                    \
        if (RELOAD) {  /* refill ring slot for step TT+4 */                  \
            const float* xp = xb + (size_t)((TT) + 4) * RNN_H;               \
            _Pragma("unroll")                                                \
            for (int q = 0; q < 4; ++q)                                      \
                xr[S][q] = *(const float4*)&xp[q * 4];                       \
        }                                                                    \
        {                                                                    \
            const float4* h1p = (const float4*)&h1s[k0];                     \
            _Pragma("unroll")                                                \
            for (int q = 0; q < 4; ++q) {                                    \
                float4 hv = h1p[q];                                          \
                acch = fmaf(whh0[q].x, hv.x, acch);                          \
                acch = fmaf(whh0[q].y, hv.y, acch);                          \
                acch = fmaf(whh0[q].z, hv.z, acch);                          \
                acch = fmaf(whh0[q].w, hv.w, acch);                          \
            }                                                                \
        }                                                                    \
        float a1 = accx + acch;                                              \
        a1 += __shfl_xor(a1, 32);                                            \
        const float h1v = fast_tanh(a1 + bias1);                             \
        h1s[j] = h1v; /* both halves write identical value */                \
        __asm__ volatile("" ::: "memory");                                   \
        /* layer 2: h1-dot + h2-dot */                                       \
        float acca = 0.f, accb = 0.f;                                        \
        {                                                                    \
            const float4* h1q = (const float4*)&h1s[k0];                     \
            const float4* h2q = (const float4*)&h2s[k0];                     \
            _Pragma("unroll")                                                \
            for (int q = 0; q < 4; ++q) {                                    \
                float4 av = h1q[q];                                          \
                float4 bv = h2q[q];                                          \
                acca = fmaf(wih1[q].x, av.x, acca);                          \
                acca = fmaf(wih1[q].y, av.y, acca);                          \
                acca = fmaf(wih1[q].z, av.z, acca);                          \
                acca = fmaf(wih1[q].w, av.w, acca);                          \
                accb = fmaf(whh1[q].x, bv.x, accb);                          \
                accb = fmaf(whh1[q].y, bv.y, accb);                          \
                accb = fmaf(whh1[q].z, bv.z, accb);                          \
                accb = fmaf(whh1[q].w, bv.w, accb);                          \
            }                                                                \
        }                                                                    \
        float a2 = acca + accb;                                              \
        a2 += __shfl_xor(a2, 32);                                            \
        const float h2v = fast_tanh(a2 + bias2);                             \
        h2s[j] = h2v;                                                        \
        __asm__ volatile("" ::: "memory");                                   \
    }

    for (int t = 0; t < RNN_T - 4; t += 4) {
        RNN_STEP(0, t + 0, 1)
        RNN_STEP(1, t + 1, 1)
        RNN_STEP(2, t + 2, 1)
        RNN_STEP(3, t + 3, 1)
    }
    // final 4 steps: no reload (avoids OOB prefetch)
    RNN_STEP(0, RNN_T - 4, 0)
    RNN_STEP(1, RNN_T - 3, 0)
    RNN_STEP(2, RNN_T - 2, 0)
    RNN_STEP(3, RNN_T - 1, 0)
#undef RNN_STEP

    // FC epilogue: logits[b][c] = fc_w[c] . h2 + fc_b[c]
    if (lane < RNN_C) {
        float s = fc_b[lane];
#pragma unroll
        for (int jj = 0; jj < RNN_H; ++jj)
            s = fmaf(fc_w[lane * RNN_H + jj], h2s[jj], s);
        out[b * RNN_C + lane] = s;
    }
}

extern "C" void kernel_launch(void* const* d_in, const int* in_sizes, int n_in,
                              void* d_out, int out_size, void* d_ws, size_t ws_size,
                              hipStream_t stream) {
    const float* x     = (const float*)d_in[0];
    const float* W_ih0 = (const float*)d_in[1];
    const float* W_hh0 = (const float*)d_in[2];
    const float* b_ih0 = (const float*)d_in[3];
    const float* b_hh0 = (const float*)d_in[4];
    const float* W_ih1 = (const float*)d_in[5];
    const float* W_hh1 = (const float*)d_in[6];
    const float* b_ih1 = (const float*)d_in[7];
    const float* b_hh1 = (const float*)d_in[8];
    const float* fc_w  = (const float*)d_in[9];
    const float* fc_b  = (const float*)d_in[10];
    float* out = (float*)d_out;

    rnn2_kernel<<<RNN_B, 64, 0, stream>>>(x, W_ih0, W_hh0, b_ih0, b_hh0,
                                          W_ih1, W_hh1, b_ih1, b_hh1,
                                          fc_w, fc_b, out);
}

// Round 2
// 484.816 us; speedup vs baseline: 1.4593x; 1.4593x over previous
//
#include <hip/hip_runtime.h>

#define RH 32
#define RT 2048
#define RB 512
#define RC 10

// LDS float offsets
#define XRING 0      // 16 slots x 32 floats = 512 (two 1KiB chunk halves)
#define H1OFF 512
#define H2OFF 544
#define TRASH 576
#define LDSF  608

// tanh(x) = 1 - 2/(exp(2x)+1); saturates correctly at +/-inf.
__device__ __forceinline__ float fast_tanh(float x) {
    float e = __builtin_amdgcn_exp2f(x * 2.88539008177792681472f); // 2*log2(e)
    return fmaf(-2.0f, __builtin_amdgcn_rcpf(e + 1.0f), 1.0f);
}

__global__ __launch_bounds__(64) void rnn2_kernel(
    const float* __restrict__ x,
    const float* __restrict__ W_ih0, const float* __restrict__ W_hh0,
    const float* __restrict__ b_ih0, const float* __restrict__ b_hh0,
    const float* __restrict__ W_ih1, const float* __restrict__ W_hh1,
    const float* __restrict__ b_ih1, const float* __restrict__ b_hh1,
    const float* __restrict__ fc_w, const float* __restrict__ fc_b,
    float* __restrict__ out)
{
    __shared__ float lds[LDSF];
    const int b    = blockIdx.x;
    const int lane = threadIdx.x;     // one wave per block/batch
    const int j    = lane & 31;       // output row
    const int half = lane >> 5;       // 0: layer1 at step t, 1: layer2 at step t-1

    // Per-lane weights in registers: full rows (no k-split).
    const float* WA = half ? W_hh1 : W_hh0;   // recurrent operand weights
    const float* WB = half ? W_ih1 : W_ih0;   // "input" operand weights
    float wa[RH], wb[RH];
#pragma unroll
    for (int q = 0; q < 8; ++q) {
        float4 va = *(const float4*)&WA[j * RH + q * 4];
        float4 vb = *(const float4*)&WB[j * RH + q * 4];
        wa[q*4+0]=va.x; wa[q*4+1]=va.y; wa[q*4+2]=va.z; wa[q*4+3]=va.w;
        wb[q*4+0]=vb.x; wb[q*4+1]=vb.y; wb[q*4+2]=vb.z; wb[q*4+3]=vb.w;
    }
    const float bias = half ? (b_ih1[j] + b_hh1[j]) : (b_ih0[j] + b_hh0[j]);

    if (lane < RH) { lds[H1OFF + lane] = 0.0f; lds[H2OFF + lane] = 0.0f; }
    __syncthreads();

    // Per-lane fixed pointers
    const float* pA  = &lds[half ? H2OFF : H1OFF];  // recurrent input vector
    const float* ph1 = &lds[H1OFF];                 // layer2's "input" vector
    float* wr_norm   = &lds[(half ? H2OFF : H1OFF) + j];
    float* wr_first  = half ? &lds[TRASH + j] : &lds[H1OFF + j];  // t=0: h2 invalid
    float* wr_last   = half ? &lds[H2OFF + j] : &lds[TRASH + j];  // t=T:  h1 invalid

    // x staging: chunk c = 8 steps = 1KiB, direct global->LDS, ring of 2 chunks.
    const float* xg = x + (size_t)b * RT * RH + lane * 4;  // per-lane 16B piece
#define STAGE(c)  __builtin_amdgcn_global_load_lds( \
        (const __attribute__((address_space(1))) void*)(xg + (c) * 256), \
        (__attribute__((address_space(3))) void*)&lds[XRING + ((c) & 1) * 256], \
        16, 0, 0)

#define STEP(XB, S, WRP) do {                                                \
        const float4* Af = (const float4*)pA;                                \
        const float4* Bf = (const float4*)(half ? ph1 : ((XB) + (S) * RH));  \
        float sA0=0.f,sA1=0.f,sA2=0.f,sA3=0.f;                               \
        float sB0=0.f,sB1=0.f,sB2=0.f,sB3=0.f;                               \
        _Pragma("unroll")                                                    \
        for (int q = 0; q < 4; ++q) {                                        \
            float4 a0 = Af[q], a1 = Af[q+4];                                 \
            float4 b0 = Bf[q], b1 = Bf[q+4];                                 \
            sA0 = fmaf(wa[q*4+0], a0.x, sA0);                                \
            sA1 = fmaf(wa[q*4+1], a0.y, sA1);                                \
            sA2 = fmaf(wa[q*4+2], a0.z, sA2);                                \
            sA3 = fmaf(wa[q*4+3], a0.w, sA3);                                \
            sA0 = fmaf(wa[16+q*4+0], a1.x, sA0);                             \
            sA1 = fmaf(wa[16+q*4+1], a1.y, sA1);                             \
            sA2 = fmaf(wa[16+q*4+2], a1.z, sA2);                             \
            sA3 = fmaf(wa[16+q*4+3], a1.w, sA3);                             \
            sB0 = fmaf(wb[q*4+0], b0.x, sB0);                                \
            sB1 = fmaf(wb[q*4+1], b0.y, sB1);                                \
            sB2 = fmaf(wb[q*4+2], b0.z, sB2);                                \
            sB3 = fmaf(wb[q*4+3], b0.w, sB3);                                \
            sB0 = fmaf(wb[16+q*4+0], b1.x, sB0);                             \
            sB1 = fmaf(wb[16+q*4+1], b1.y, sB1);                             \
            sB2 = fmaf(wb[16+q*4+2], b1.z, sB2);                             \
            sB3 = fmaf(wb[16+q*4+3], b1.w, sB3);                             \
        }                                                                    \
        float r = ((sA0+sA1)+(sA2+sA3)) + ((sB0+sB1)+(sB2+sB3));             \
        *(WRP) = fast_tanh(r + bias);                                        \
        __asm__ volatile("" ::: "memory");                                   \
    } while (0)

    STAGE(0);
    STAGE(1);

    // chunk 0 (t = 0..7): t=0 writes layer2 result to trash
    STAGE(2);
    __asm__ volatile("s_waitcnt vmcnt(2)" ::: "memory");
    {
        const float* xb = &lds[XRING];
        STEP(xb, 0, wr_first);
        STEP(xb, 1, wr_norm); STEP(xb, 2, wr_norm); STEP(xb, 3, wr_norm);
        STEP(xb, 4, wr_norm); STEP(xb, 5, wr_norm); STEP(xb, 6, wr_norm);
        STEP(xb, 7, wr_norm);
    }
    // chunks 1..253: steady state, 2 staged chunks in flight
    for (int c = 1; c <= 253; ++c) {
        STAGE(c + 2);
        __asm__ volatile("s_waitcnt vmcnt(2)" ::: "memory");
        const float* xb = &lds[XRING + (c & 1) * 256];
        STEP(xb, 0, wr_norm); STEP(xb, 1, wr_norm); STEP(xb, 2, wr_norm);
        STEP(xb, 3, wr_norm); STEP(xb, 4, wr_norm); STEP(xb, 5, wr_norm);
        STEP(xb, 6, wr_norm); STEP(xb, 7, wr_norm);
    }
    // chunk 254 (even -> ring half 0)
    __asm__ volatile("s_waitcnt vmcnt(1)" ::: "memory");
    {
        const float* xb = &lds[XRING];
        STEP(xb, 0, wr_norm); STEP(xb, 1, wr_norm); STEP(xb, 2, wr_norm);
        STEP(xb, 3, wr_norm); STEP(xb, 4, wr_norm); STEP(xb, 5, wr_norm);
        STEP(xb, 6, wr_norm); STEP(xb, 7, wr_norm);
    }
    // chunk 255
    __asm__ volatile("s_waitcnt vmcnt(0)" ::: "memory");
    {
        const float* xb = &lds[XRING + 256];
        STEP(xb, 0, wr_norm); STEP(xb, 1, wr_norm); STEP(xb, 2, wr_norm);
        STEP(xb, 3, wr_norm); STEP(xb, 4, wr_norm); STEP(xb, 5, wr_norm);
        STEP(xb, 6, wr_norm); STEP(xb, 7, wr_norm);
    }
    // final iteration t = 2048: layer2 computes h2(2047); layer1 result -> trash
    {
        const float* xb = &lds[XRING];   // stale x, result discarded
        STEP(xb, 0, wr_last);
    }
#undef STEP
#undef STAGE

    // FC epilogue: logits[b][c] = fc_w[c] . h2_final + fc_b[c]
    if (lane < RC) {
        float s = fc_b[lane];
#pragma unroll
        for (int k = 0; k < RH; ++k)
            s = fmaf(fc_w[lane * RH + k], lds[H2OFF + k], s);
        out[b * RC + lane] = s;
    }
}

extern "C" void kernel_launch(void* const* d_in, const int* in_sizes, int n_in,
                              void* d_out, int out_size, void* d_ws, size_t ws_size,
                              hipStream_t stream) {
    const float* x     = (const float*)d_in[0];
    const float* W_ih0 = (const float*)d_in[1];
    const float* W_hh0 = (const float*)d_in[2];
    const float* b_ih0 = (const float*)d_in[3];
    const float* b_hh0 = (const float*)d_in[4];
    const float* W_ih1 = (const float*)d_in[5];
    const float* W_hh1 = (const float*)d_in[6];
    const float* b_ih1 = (const float*)d_in[7];
    const float* b_hh1 = (const float*)d_in[8];
    const float* fc_w  = (const float*)d_in[9];
    const float* fc_b  = (const float*)d_in[10];
    float* out = (float*)d_out;

    rnn2_kernel<<<RB, 64, 0, stream>>>(x, W_ih0, W_hh0, b_ih0, b_hh0,
                                       W_ih1, W_hh1, b_ih1, b_hh1,
                                       fc_w, fc_b, out);
}